// Round 15
// baseline (146.748 us; speedup 1.0000x reference)
//
#include <hip/hip_runtime.h>
#include <stdint.h>
#include <stddef.h>

#define B_      8
#define T_      16
#define NX_     256
#define NZ_     64
#define D_      1024
#define HEADS_  8
#define DHEAD_  64
#define INNER_  512
#define NKEY_   320          // NX_ + NZ_
#define NBT_    128          // B_*T_

typedef __attribute__((ext_vector_type(8))) short     short8;
typedef __attribute__((ext_vector_type(4))) float     f32x4;

__device__ __forceinline__ unsigned short f2bf(float f) {
    union { float f; unsigned int u; } v; v.f = f;
    unsigned int u = v.u;
    return (unsigned short)((u + 0x7fffu + ((u >> 16) & 1u)) >> 16);
}

__device__ __forceinline__ void async16(unsigned short* lds, const unsigned short* g) {
    __builtin_amdgcn_global_load_lds(
        (const __attribute__((address_space(1))) void*)g,
        (__attribute__((address_space(3))) void*)lds, 16, 0, 0);
}

// bijective XCD-chunked swizzle over L live blocks (m204)
__device__ __forceinline__ int xcd_swz(int bid, int L) {
    int q = L >> 3, r = L & 7;
    int xcd = bid & 7, idx = bid >> 3;
    return (xcd < r ? xcd * (q + 1) : r * (q + 1) + (xcd - r) * q) + idx;
}

// ---------------------------------------------------------------------------
// fused prep + LN (R14-proven). blocks 0..8191: weight transpose; block 8192:
// mask + wave-parallel compaction; blocks 8193..49152: LayerNorm -> kvin.
// ---------------------------------------------------------------------------
__global__ __launch_bounds__(256) void prep_ln_kernel(
        const float* __restrict__ Wq, const float* __restrict__ Wkv,
        const float* __restrict__ Wo, const unsigned char* __restrict__ mraw,
        const float* __restrict__ x, const float* __restrict__ lat,
        const float* __restrict__ gm, const float* __restrict__ bm,
        const float* __restrict__ gl, const float* __restrict__ bl,
        unsigned short* __restrict__ WqT, unsigned short* __restrict__ WkvT,
        unsigned short* __restrict__ WoT, unsigned short* __restrict__ kvin,
        int* __restrict__ maskN, int* __restrict__ meta,
        int* __restrict__ liveBt, int* __restrict__ grpSrc,
        int* __restrict__ grpOut) {
    int bid = blockIdx.x;
    if (bid < 8192) {                        // ---- weight transpose
        size_t id = (size_t)bid * 256 + threadIdx.x;
        if (id < 524288) {                   // WqT[512][1024] <- Wq[1024][512]
            int n = (int)(id >> 10), k = (int)(id & 1023);
            WqT[id] = f2bf(Wq[(size_t)k * 512 + n]);
        } else if (id < 524288 + 1048576) {  // WkvT[1024][1024]
            size_t j = id - 524288;
            int n = (int)(j >> 10), k = (int)(j & 1023);
            WkvT[j] = f2bf(Wkv[(size_t)k * 1024 + n]);
        } else {                             // WoT[1024][512]
            size_t j = id - 1572864;
            int n = (int)(j >> 9), k = (int)(j & 511);
            WoT[j] = f2bf(Wo[(size_t)k * 1024 + n]);
        }
        return;
    }
    if (bid == 8192) {                       // ---- mask + compaction lists
        int l = threadIdx.x;
        if (l >= 64) return;
        unsigned char b0 = mraw[l];
        unsigned char b1 = mraw[l + 64];
        bool nz = ((l & 3) != 0 && b0 != 0) || (((l + 64) & 3) != 0 && b1 != 0);
        unsigned long long ball = __ballot(nz ? 1 : 0);
        bool isBool = (ball != 0ull);
        int v0, v1;
        if (isBool) { v0 = b0; v1 = b1; }
        else        { v0 = mraw[4 * l]; v1 = mraw[4 * (l + 64)]; }
        v0 = v0 ? 1 : 0; v1 = v1 ? 1 : 0;
        maskN[l]      = v0;
        maskN[l + 64] = v1;
        unsigned long long B0 = __ballot(v0), B1 = __ballot(v1);
        int n0 = __popcll(B0);
        int nl = n0 + __popcll(B1);
        unsigned long long below = (1ull << l) - 1ull;
        if (v0) {
            int p = __popcll(B0 & below);
            liveBt[p] = l;
            #pragma unroll
            for (int g = 0; g < 5; g++) {
                grpSrc[5 * p + g] = l * NKEY_ + g * 64;
                grpOut[5 * p + g] = (l << 16) | (g * 64);
            }
        }
        if (v1) {
            int p = n0 + __popcll(B1 & below);
            int bt = l + 64;
            liveBt[p] = bt;
            #pragma unroll
            for (int g = 0; g < 5; g++) {
                grpSrc[5 * p + g] = bt * NKEY_ + g * 64;
                grpOut[5 * p + g] = (bt << 16) | (g * 64);
            }
        }
        if (l == 0) {
            int lastBt = 0;
            if (B1) lastBt = 64 + (63 - __clzll(B1));
            else if (B0) lastBt = 63 - __clzll(B0);
            int ng = 5 * nl;
            if (nl & 1) liveBt[nl] = lastBt;
            if (ng & 1) { grpSrc[ng] = lastBt * NKEY_ + 256;
                          grpOut[ng] = (lastBt << 16) | 256; }
            meta[0] = nl;
            meta[1] = (ng + 1) >> 1;
            meta[2] = (nl + 1) >> 1;
        }
        return;
    }
    // ---- LayerNorm
    int row = bid - 8193;
    const float* src; unsigned short* dst; const float* g; const float* b;
    int bt;
    if (row < NBT_ * NX_) {
        bt = row >> 8;
        src = x + (size_t)row * D_;
        dst = kvin + ((size_t)bt * NKEY_ + (row & 255)) * D_;
        g = gm; b = bm;
    } else {
        int r = row - NBT_ * NX_;
        bt = r >> 6;
        src = lat + (size_t)r * D_;
        dst = kvin + ((size_t)bt * NKEY_ + 256 + (r & 63)) * D_;
        g = gl; b = bl;
    }
    int t = threadIdx.x;
    __shared__ int liveFlag;
    if (t < 64) {
        unsigned char c0 = mraw[t];
        unsigned char c1 = mraw[t + 64];
        bool nz = ((t & 3) != 0 && c0 != 0) || (((t + 64) & 3) != 0 && c1 != 0);
        unsigned long long ball = __ballot(nz ? 1 : 0);
        bool isBool = (ball != 0ull);
        if (t == 0) {
            int v = isBool ? mraw[bt] : mraw[4 * bt];
            liveFlag = v ? 1 : 0;
        }
    }
    __syncthreads();
    if (!liveFlag) return;
    float4 v = reinterpret_cast<const float4*>(src)[t];
    float s  = v.x + v.y + v.z + v.w;
    float sq = v.x * v.x + v.y * v.y + v.z * v.z + v.w * v.w;
    #pragma unroll
    for (int off = 32; off > 0; off >>= 1) {
        s  += __shfl_down(s, off);
        sq += __shfl_down(sq, off);
    }
    __shared__ float red[8];
    int wid = t >> 6;
    if ((t & 63) == 0) { red[wid] = s; red[4 + wid] = sq; }
    __syncthreads();
    float stot = red[0] + red[1] + red[2] + red[3];
    float qtot = red[4] + red[5] + red[6] + red[7];
    float mean = stot * (1.0f / 1024.0f);
    float var  = qtot * (1.0f / 1024.0f) - mean * mean;
    float rstd = rsqrtf(var + 1e-5f);
    float4 gv = reinterpret_cast<const float4*>(g)[t];
    float4 bv = reinterpret_cast<const float4*>(b)[t];
    ushort4 o;
    o.x = f2bf((v.x - mean) * rstd * gv.x + bv.x);
    o.y = f2bf((v.y - mean) * rstd * gv.y + bv.y);
    o.z = f2bf((v.z - mean) * rstd * gv.z + bv.z);
    o.w = f2bf((v.w - mean) * rstd * gv.w + bv.w);
    *reinterpret_cast<ushort4*>(dst + 4 * t) = o;
}

// ---------------------------------------------------------------------------
// 128x256 8-wave GEMM body (halves L2 traffic vs 128x128): BK=32, wave-grid
// 2Mx4N (each wave 64x64 = proven R12 per-wave workload: acc[4][4], 16 MFMA
// + 8 ds_read/step, ~100 VGPR -> 16 waves/CU residency), 48 KB LDS dbuf,
// counted vmcnt(3). Staging from the wave-uniform gload_lds rule: wave w
// issues A-slice w (rows 16w..16w+15) + B-slices 2w,2w+1 (rows 32w..32w+31);
// lane l covers row +l>>2, 16B slot l&3.
// MODE 0: q  = zn(live) @ WqT (N=512, NT=2), *0.125, bf16
// MODE 1: kv = kvin(live grps) @ WkvT (N=1024, NT=4) -> k / vT split
// MODE 2: out = ao(live) @ WoT (K=512, N=1024, NT=4), f32
// ---------------------------------------------------------------------------
template<int MODE>
__device__ __forceinline__ void gemm256_body(
        int bid, unsigned short* As, unsigned short* Bs,
        const unsigned short* __restrict__ A,
        const unsigned short* __restrict__ BT,
        const int* __restrict__ meta,
        const int* __restrict__ liveBt,
        const int* __restrict__ grpSrc,
        const int* __restrict__ grpOut,
        unsigned short* __restrict__ o_q,
        unsigned short* __restrict__ o_k,
        unsigned short* __restrict__ o_v,
        float* __restrict__ o_f) {
    constexpr int K     = (MODE == 2) ? 512 : 1024;
    constexpr int NSTEP = K / 32;                              // even
    constexpr int NTSH  = (MODE == 0) ? 1 : 2;                 // log2(N/256)

    int lim = (MODE == 1) ? meta[1] : meta[2];
    int L = lim << NTSH;
    if (bid >= L) return;
    int wg = xcd_swz(bid, L);
    int mt = wg >> NTSH;
    int nt = wg & ((1 << NTSH) - 1);
    int n0 = nt * 256;
    int t = threadIdx.x;
    int lane = t & 63, w = t >> 6;                 // 8 waves
    int lr = lane & 15, lg = lane >> 4;
    int wm = w >> 2, wn = w & 3;                   // wave grid 2M x 4N

    // staging pointers (per-lane, derived from wave-uniform dest rule)
    const unsigned short* aptr;                    // A-slice w: rows 16w..
    const unsigned short* bptr[2];                 // B-slices 2w+jb: rows 32w..
    {
        int R = w * 16 + (lane >> 2);              // A row in 128-tile
        int grp = w >> 2;                          // R>>6
        int rin = R & 63;
        size_t srow;
        if (MODE == 0) {
            int bt = liveBt[2 * mt + grp];
            srow = (size_t)bt * NKEY_ + 256 + rin;
        } else if (MODE == 1) {
            srow = (size_t)grpSrc[2 * mt + grp] + rin;
        } else {
            int bt = liveBt[2 * mt + grp];
            srow = (size_t)bt * 64 + rin;
        }
        aptr = A + srow * K + (lane & 3) * 8;
        #pragma unroll
        for (int jb = 0; jb < 2; jb++) {
            int Rb = w * 32 + jb * 16 + (lane >> 2);   // B row in 256-tile
            bptr[jb] = BT + (size_t)(n0 + Rb) * K + (lane & 3) * 8;
        }
    }

    f32x4 acc[4][4];
    #pragma unroll
    for (int i = 0; i < 4; i++)
        #pragma unroll
        for (int j = 0; j < 4; j++) acc[i][j] = (f32x4){0.f, 0.f, 0.f, 0.f};

    auto stage = [&](int buf) {
        async16(As + buf * 4096 + w * 512, aptr);             // A: 1 issue
        aptr += 32;
        #pragma unroll
        for (int jb = 0; jb < 2; jb++) {                      // B: 2 issues
            async16(Bs + buf * 8192 + (w * 2 + jb) * 512, bptr[jb]);
            bptr[jb] += 32;
        }
    };
    auto compute = [&](int buf) {
        short8 af[4], bf[4];
        #pragma unroll
        for (int mi = 0; mi < 4; mi++)
            af[mi] = *reinterpret_cast<const short8*>(
                &As[buf * 4096 + (wm * 64 + mi * 16 + lr) * 32 + lg * 8]);
        #pragma unroll
        for (int ni = 0; ni < 4; ni++)
            bf[ni] = *reinterpret_cast<const short8*>(
                &Bs[buf * 8192 + (wn * 64 + ni * 16 + lr) * 32 + lg * 8]);
        #pragma unroll
        for (int mi = 0; mi < 4; mi++)
            #pragma unroll
            for (int ni = 0; ni < 4; ni++)
                acc[mi][ni] = __builtin_amdgcn_mfma_f32_16x16x32_bf16(
                    af[mi], bf[ni], acc[mi][ni], 0, 0, 0);
    };

    #define FULL_STEP(CUR)                                              \
        stage((CUR) ^ 1);                                               \
        asm volatile("s_waitcnt vmcnt(3)" ::: "memory");                \
        __builtin_amdgcn_s_barrier();                                   \
        compute(CUR);                                                   \
        asm volatile("s_waitcnt lgkmcnt(0)" ::: "memory");              \
        __builtin_amdgcn_s_barrier();

    stage(0);
    #pragma unroll 1
    for (int ks2 = 0; ks2 < NSTEP / 2 - 1; ks2++) {
        FULL_STEP(0)
        FULL_STEP(1)
    }
    FULL_STEP(0)
    asm volatile("s_waitcnt vmcnt(0)" ::: "memory");
    __builtin_amdgcn_s_barrier();
    compute(1);
    #undef FULL_STEP

    #pragma unroll
    for (int mi = 0; mi < 4; mi++)
        #pragma unroll
        for (int ni = 0; ni < 4; ni++) {
            int rr = mi * 16 + lg * 4;                     // row in 64-group
            int c  = n0 + wn * 64 + ni * 16 + lr;
            if (MODE == 0) {
                int bt = liveBt[2 * mt + wm];
                #pragma unroll
                for (int r = 0; r < 4; r++)
                    o_q[((size_t)bt * 64 + rr + r) * 512 + c] =
                        f2bf(acc[mi][ni][r] * 0.125f);
            } else if (MODE == 1) {
                int enc = grpOut[2 * mt + wm];
                int bt = enc >> 16, krow = (enc & 0xffff) + rr;
                if (c < 512) {
                    #pragma unroll
                    for (int r = 0; r < 4; r++)
                        o_k[((size_t)bt * NKEY_ + krow + r) * 512 + c] =
                            f2bf(acc[mi][ni][r]);
                } else {
                    ushort4 pv;
                    pv.x = f2bf(acc[mi][ni][0]); pv.y = f2bf(acc[mi][ni][1]);
                    pv.z = f2bf(acc[mi][ni][2]); pv.w = f2bf(acc[mi][ni][3]);
                    *reinterpret_cast<ushort4*>(
                        o_v + ((size_t)bt * 512 + (c - 512)) * NKEY_ + krow) = pv;
                }
            } else {
                int bt = liveBt[2 * mt + wm];
                #pragma unroll
                for (int r = 0; r < 4; r++)
                    o_f[((size_t)bt * 64 + rr + r) * 1024 + c] = acc[mi][ni][r];
            }
        }
}

// fused kv-GEMM (blocks 0..1279) + q-GEMM (blocks 1280..1407)
__global__ __launch_bounds__(512, 2) void gemm_kvq_kernel(
        const unsigned short* __restrict__ kvin,
        const unsigned short* __restrict__ WkvT,
        const unsigned short* __restrict__ WqT,
        const int* __restrict__ meta,
        const int* __restrict__ liveBt,
        const int* __restrict__ grpSrc,
        const int* __restrict__ grpOut,
        unsigned short* __restrict__ o_q,
        unsigned short* __restrict__ o_k,
        unsigned short* __restrict__ o_v) {
    __shared__ __align__(16) unsigned short As[2 * 4096];
    __shared__ __align__(16) unsigned short Bs[2 * 8192];
    int bid = blockIdx.x;
    if (bid < 1280)
        gemm256_body<1>(bid, As, Bs, kvin, WkvT, meta, liveBt, grpSrc, grpOut,
                        o_q, o_k, o_v, (float*)0);
    else
        gemm256_body<0>(bid - 1280, As, Bs, kvin, WqT, meta, liveBt, grpSrc,
                        grpOut, o_q, o_k, o_v, (float*)0);
}

__global__ __launch_bounds__(512, 2) void gemm_out_kernel(
        const unsigned short* __restrict__ ab,
        const unsigned short* __restrict__ WoT,
        const int* __restrict__ meta,
        const int* __restrict__ liveBt,
        const int* __restrict__ grpSrc,
        const int* __restrict__ grpOut,
        float* __restrict__ o_f) {
    __shared__ __align__(16) unsigned short As[2 * 4096];
    __shared__ __align__(16) unsigned short Bs[2 * 8192];
    gemm256_body<2>(blockIdx.x, As, Bs, ab, WoT, meta, liveBt, grpSrc, grpOut,
                    (unsigned short*)0, (unsigned short*)0, (unsigned short*)0,
                    o_f);
}

// ---------------------------------------------------------------------------
// fused attention per live (bt,h) + zero-fill tail (blocks 1024..1151)
// ---------------------------------------------------------------------------
__global__ __launch_bounds__(256) void attn_kernel(
        const unsigned short* __restrict__ q,
        const unsigned short* __restrict__ kbuf,
        const unsigned short* __restrict__ vbuf,   // vT [bt][512][320]
        const int* __restrict__ meta,
        const int* __restrict__ liveBt,
        const int* __restrict__ maskN,
        unsigned short* __restrict__ ao,
        float* __restrict__ out_f) {
    int bid = blockIdx.x;
    if (bid >= 1024) {                             // zero-fill tail
        int bt = bid - 1024;
        if (maskN[bt]) return;
        float4* p = reinterpret_cast<float4*>(out_f + (size_t)bt * 65536);
        float4 z = make_float4(0.f, 0.f, 0.f, 0.f);
        #pragma unroll
        for (int k = 0; k < 64; k++) p[k * 256 + threadIdx.x] = z;
        return;
    }
    int L = meta[0] << 3;
    if (bid >= L) return;
    int wg = xcd_swz(bid, L);
    int i = wg >> 3, h = wg & 7;
    int bt = liveBt[i];
    int t = threadIdx.x, w = t >> 6, lane = t & 63;
    int lr = lane & 15, lg = lane >> 4;
    __shared__ __align__(16) unsigned short attn_s[4][16][328];

    const unsigned short* qrow = q + ((size_t)bt * 64 + w * 16 + lr) * 512 + h * 64;
    short8 qa0 = *reinterpret_cast<const short8*>(qrow + lg * 8);
    short8 qa1 = *reinterpret_cast<const short8*>(qrow + 32 + lg * 8);

    f32x4 acc[20];
    #pragma unroll
    for (int i2 = 0; i2 < 20; i2++) acc[i2] = (f32x4){0.f, 0.f, 0.f, 0.f};

    const unsigned short* kb = kbuf + (size_t)bt * NKEY_ * 512 + h * 64;
    #pragma unroll
    for (int nt2 = 0; nt2 < 20; nt2++) {
        const unsigned short* krow = kb + (size_t)(nt2 * 16 + lr) * 512;
        short8 b0 = *reinterpret_cast<const short8*>(krow + lg * 8);
        short8 b1 = *reinterpret_cast<const short8*>(krow + 32 + lg * 8);
        acc[nt2] = __builtin_amdgcn_mfma_f32_16x16x32_bf16(qa0, b0, acc[nt2], 0, 0, 0);
        acc[nt2] = __builtin_amdgcn_mfma_f32_16x16x32_bf16(qa1, b1, acc[nt2], 0, 0, 0);
    }

    float mx[4], sm[4];
    #pragma unroll
    for (int r = 0; r < 4; r++) mx[r] = -1e30f;
    #pragma unroll
    for (int nt2 = 0; nt2 < 20; nt2++)
        #pragma unroll
        for (int r = 0; r < 4; r++) mx[r] = fmaxf(mx[r], acc[nt2][r]);
    #pragma unroll
    for (int r = 0; r < 4; r++) {
        #pragma unroll
        for (int off = 1; off < 16; off <<= 1)
            mx[r] = fmaxf(mx[r], __shfl_xor(mx[r], off));
        sm[r] = 0.f;
    }
    #pragma unroll
    for (int nt2 = 0; nt2 < 20; nt2++)
        #pragma unroll
        for (int r = 0; r < 4; r++) {
            float p = __expf(acc[nt2][r] - mx[r]);
            acc[nt2][r] = p;
            sm[r] += p;
        }
    #pragma unroll
    for (int r = 0; r < 4; r++) {
        #pragma unroll
        for (int off = 1; off < 16; off <<= 1)
            sm[r] += __shfl_xor(sm[r], off);
        sm[r] = 1.0f / sm[r];
    }
    #pragma unroll
    for (int nt2 = 0; nt2 < 20; nt2++)
        #pragma unroll
        for (int r = 0; r < 4; r++)
            attn_s[w][lg * 4 + r][nt2 * 16 + lr] = f2bf(acc[nt2][r] * sm[r]);
    __syncthreads();

    f32x4 o[4];
    #pragma unroll
    for (int i2 = 0; i2 < 4; i2++) o[i2] = (f32x4){0.f, 0.f, 0.f, 0.f};
    const unsigned short* vb = vbuf + (size_t)bt * 512 * NKEY_ + (size_t)h * 64 * NKEY_;
    #pragma unroll
    for (int kc = 0; kc < 10; kc++) {
        short8 pa = *reinterpret_cast<const short8*>(&attn_s[w][lr][kc * 32 + lg * 8]);
        #pragma unroll
        for (int ni = 0; ni < 4; ni++) {
            short8 vf = *reinterpret_cast<const short8*>(
                vb + (size_t)(ni * 16 + lr) * NKEY_ + kc * 32 + lg * 8);
            o[ni] = __builtin_amdgcn_mfma_f32_16x16x32_bf16(pa, vf, o[ni], 0, 0, 0);
        }
    }
    #pragma unroll
    for (int ni = 0; ni < 4; ni++)
        #pragma unroll
        for (int r = 0; r < 4; r++)
            ao[((size_t)bt * 64 + w * 16 + lg * 4 + r) * 512 + h * 64 + ni * 16 + lr] =
                f2bf(o[ni][r]);
}

// ---------------------------------------------------------------------------
extern "C" void kernel_launch(void* const* d_in, const int* in_sizes, int n_in,
                              void* d_out, int out_size, void* d_ws, size_t ws_size,
                              hipStream_t stream) {
    const float* x            = (const float*)d_in[0];
    const float* lat          = (const float*)d_in[1];
    const unsigned char* mraw = (const unsigned char*)d_in[2];
    const float* gm           = (const float*)d_in[3];
    const float* bm           = (const float*)d_in[4];
    const float* gl           = (const float*)d_in[5];
    const float* bl           = (const float*)d_in[6];
    const float* Wq           = (const float*)d_in[7];
    const float* Wkv          = (const float*)d_in[8];
    const float* Wo           = (const float*)d_in[9];
    float* out = (float*)d_out;

    char* ws = (char*)d_ws;
    int* maskN  = (int*)(ws + 0);          // 512 B
    int* meta   = (int*)(ws + 512);        // 64 B
    int* liveBt = (int*)(ws + 1024);       // 640 B
    int* grpSrc = (int*)(ws + 2048);       // ~2.6 KB
    int* grpOut = (int*)(ws + 5120);       // ~2.6 KB
    size_t off = 8192;
    unsigned short* WqT  = (unsigned short*)(ws + off); off += 1048576;   // 512*1024*2
    unsigned short* WkvT = (unsigned short*)(ws + off); off += 2097152;   // 1024*1024*2
    unsigned short* WoT  = (unsigned short*)(ws + off); off += 1048576;   // 1024*512*2
    unsigned short* kvin = (unsigned short*)(ws + off); off += 83886080;  // 128*320*1024*2
    unsigned short* qb   = (unsigned short*)(ws + off); off += 8388608;   // 128*64*512*2
    unsigned short* kb   = (unsigned short*)(ws + off); off += 41943040;  // 128*320*512*2
    unsigned short* vb   = (unsigned short*)(ws + off); off += 41943040;  // 128*512*320*2
    unsigned short* ab   = (unsigned short*)(ws + off); off += 8388608;   // 128*64*512*2

    hipLaunchKernelGGL(prep_ln_kernel, dim3(49153), dim3(256), 0, stream,
                       Wq, Wkv, Wo, mraw, x, lat, gm, bm, gl, bl,
                       WqT, WkvT, WoT, kvin, maskN, meta, liveBt, grpSrc, grpOut);
    hipLaunchKernelGGL(gemm_kvq_kernel, dim3(1408), dim3(512), 0, stream,
                       kvin, WkvT, WqT, meta, liveBt, grpSrc, grpOut,
                       qb, kb, vb);
    hipLaunchKernelGGL(attn_kernel,     dim3(1152), dim3(256), 0, stream,
                       qb, kb, vb, meta, liveBt, maskN, ab, out);
    hipLaunchKernelGGL(gemm_out_kernel, dim3(256),  dim3(512), 0, stream,
                       ab, WoT, meta, liveBt, grpSrc, grpOut, out);
}

// Round 16
// 135.323 us; speedup vs baseline: 1.0844x; 1.0844x over previous
//
#include <hip/hip_runtime.h>
#include <stdint.h>
#include <stddef.h>

#define B_      8
#define T_      16
#define NX_     256
#define NZ_     64
#define D_      1024
#define HEADS_  8
#define DHEAD_  64
#define INNER_  512
#define NKEY_   320          // NX_ + NZ_
#define NBT_    128          // B_*T_

typedef __attribute__((ext_vector_type(8))) short     short8;
typedef __attribute__((ext_vector_type(4))) float     f32x4;

__device__ __forceinline__ unsigned short f2bf(float f) {
    union { float f; unsigned int u; } v; v.f = f;
    unsigned int u = v.u;
    return (unsigned short)((u + 0x7fffu + ((u >> 16) & 1u)) >> 16);
}

__device__ __forceinline__ void async16(unsigned short* lds, const unsigned short* g) {
    __builtin_amdgcn_global_load_lds(
        (const __attribute__((address_space(1))) void*)g,
        (__attribute__((address_space(3))) void*)lds, 16, 0, 0);
}

// bijective XCD-chunked swizzle over L live blocks (m204)
__device__ __forceinline__ int xcd_swz(int bid, int L) {
    int q = L >> 3, r = L & 7;
    int xcd = bid & 7, idx = bid >> 3;
    return (xcd < r ? xcd * (q + 1) : r * (q + 1) + (xcd - r) * q) + idx;
}

// ---------------------------------------------------------------------------
// fused prep + LN. blocks 0..511: COALESCED 64x64 LDS-tile weight transpose
// (reads 256B row segments, pad-65 LDS, writes 128B bf16 row segments --
// replaces the old fully-uncoalesced scatter that over-fetched ~80MB HBM).
// block 512: mask + wave-parallel compaction. blocks 513..41472: LayerNorm.
// ---------------------------------------------------------------------------
__global__ __launch_bounds__(256) void prep_ln_kernel(
        const float* __restrict__ Wq, const float* __restrict__ Wkv,
        const float* __restrict__ Wo, const unsigned char* __restrict__ mraw,
        const float* __restrict__ x, const float* __restrict__ lat,
        const float* __restrict__ gm, const float* __restrict__ bm,
        const float* __restrict__ gl, const float* __restrict__ bl,
        unsigned short* __restrict__ WqT, unsigned short* __restrict__ WkvT,
        unsigned short* __restrict__ WoT, unsigned short* __restrict__ kvin,
        int* __restrict__ maskN, int* __restrict__ meta,
        int* __restrict__ liveBt, int* __restrict__ grpSrc,
        int* __restrict__ grpOut) {
    int bid = blockIdx.x;
    int t = threadIdx.x;
    if (bid < 512) {                         // ---- coalesced weight transpose
        const float* W; unsigned short* WT;
        int K, N, kt, nt;
        if (bid < 128)       { W = Wq;  WT = WqT;  K = 1024; N = 512;
                               kt = bid >> 3;          nt = bid & 7; }
        else if (bid < 384)  { W = Wkv; WT = WkvT; K = 1024; N = 1024;
                               kt = (bid - 128) >> 4;  nt = (bid - 128) & 15; }
        else                 { W = Wo;  WT = WoT;  K = 512;  N = 1024;
                               kt = (bid - 384) >> 4;  nt = (bid - 384) & 15; }
        int k0 = kt * 64, n0 = nt * 64;
        __shared__ float tile[64][65];       // +1 pad: 2-way banks (free)
        #pragma unroll
        for (int i = 0; i < 16; i++) {
            int idx = i * 256 + t;
            int r = idx >> 6, c = idx & 63;
            tile[r][c] = W[(size_t)(k0 + r) * N + n0 + c];
        }
        __syncthreads();
        #pragma unroll
        for (int i = 0; i < 16; i++) {
            int idx = i * 256 + t;
            int r = idx >> 6, c = idx & 63;
            WT[(size_t)(n0 + r) * K + k0 + c] = f2bf(tile[c][r]);
        }
        return;
    }
    if (bid == 512) {                        // ---- mask + compaction lists
        int l = t;
        if (l >= 64) return;
        unsigned char b0 = mraw[l];
        unsigned char b1 = mraw[l + 64];
        bool nz = ((l & 3) != 0 && b0 != 0) || (((l + 64) & 3) != 0 && b1 != 0);
        unsigned long long ball = __ballot(nz ? 1 : 0);
        bool isBool = (ball != 0ull);
        int v0, v1;
        if (isBool) { v0 = b0; v1 = b1; }
        else        { v0 = mraw[4 * l]; v1 = mraw[4 * (l + 64)]; }
        v0 = v0 ? 1 : 0; v1 = v1 ? 1 : 0;
        maskN[l]      = v0;
        maskN[l + 64] = v1;
        unsigned long long B0 = __ballot(v0), B1 = __ballot(v1);
        int n0 = __popcll(B0);
        int nl = n0 + __popcll(B1);
        unsigned long long below = (1ull << l) - 1ull;
        if (v0) {
            int p = __popcll(B0 & below);
            liveBt[p] = l;
            #pragma unroll
            for (int g = 0; g < 5; g++) {
                grpSrc[5 * p + g] = l * NKEY_ + g * 64;
                grpOut[5 * p + g] = (l << 16) | (g * 64);
            }
        }
        if (v1) {
            int p = n0 + __popcll(B1 & below);
            int bt = l + 64;
            liveBt[p] = bt;
            #pragma unroll
            for (int g = 0; g < 5; g++) {
                grpSrc[5 * p + g] = bt * NKEY_ + g * 64;
                grpOut[5 * p + g] = (bt << 16) | (g * 64);
            }
        }
        if (l == 0) {
            int lastBt = 0;
            if (B1) lastBt = 64 + (63 - __clzll(B1));
            else if (B0) lastBt = 63 - __clzll(B0);
            int ng = 5 * nl;
            if (nl & 1) liveBt[nl] = lastBt;
            if (ng & 1) { grpSrc[ng] = lastBt * NKEY_ + 256;
                          grpOut[ng] = (lastBt << 16) | 256; }
            meta[0] = nl;
            meta[1] = (ng + 1) >> 1;
            meta[2] = (nl + 1) >> 1;
        }
        return;
    }
    // ---- LayerNorm
    int row = bid - 513;
    const float* src; unsigned short* dst; const float* g; const float* b;
    int bt;
    if (row < NBT_ * NX_) {
        bt = row >> 8;
        src = x + (size_t)row * D_;
        dst = kvin + ((size_t)bt * NKEY_ + (row & 255)) * D_;
        g = gm; b = bm;
    } else {
        int r = row - NBT_ * NX_;
        bt = r >> 6;
        src = lat + (size_t)r * D_;
        dst = kvin + ((size_t)bt * NKEY_ + 256 + (r & 63)) * D_;
        g = gl; b = bl;
    }
    __shared__ int liveFlag;
    if (t < 64) {
        unsigned char c0 = mraw[t];
        unsigned char c1 = mraw[t + 64];
        bool nz = ((t & 3) != 0 && c0 != 0) || (((t + 64) & 3) != 0 && c1 != 0);
        unsigned long long ball = __ballot(nz ? 1 : 0);
        bool isBool = (ball != 0ull);
        if (t == 0) {
            int v = isBool ? mraw[bt] : mraw[4 * bt];
            liveFlag = v ? 1 : 0;
        }
    }
    __syncthreads();
    if (!liveFlag) return;
    float4 v = reinterpret_cast<const float4*>(src)[t];
    float s  = v.x + v.y + v.z + v.w;
    float sq = v.x * v.x + v.y * v.y + v.z * v.z + v.w * v.w;
    #pragma unroll
    for (int off = 32; off > 0; off >>= 1) {
        s  += __shfl_down(s, off);
        sq += __shfl_down(sq, off);
    }
    __shared__ float red[8];
    int wid = t >> 6;
    if ((t & 63) == 0) { red[wid] = s; red[4 + wid] = sq; }
    __syncthreads();
    float stot = red[0] + red[1] + red[2] + red[3];
    float qtot = red[4] + red[5] + red[6] + red[7];
    float mean = stot * (1.0f / 1024.0f);
    float var  = qtot * (1.0f / 1024.0f) - mean * mean;
    float rstd = rsqrtf(var + 1e-5f);
    float4 gv = reinterpret_cast<const float4*>(g)[t];
    float4 bv = reinterpret_cast<const float4*>(b)[t];
    ushort4 o;
    o.x = f2bf((v.x - mean) * rstd * gv.x + bv.x);
    o.y = f2bf((v.y - mean) * rstd * gv.y + bv.y);
    o.z = f2bf((v.z - mean) * rstd * gv.z + bv.z);
    o.w = f2bf((v.w - mean) * rstd * gv.w + bv.w);
    *reinterpret_cast<ushort4*>(dst + 4 * t) = o;
}

// ---------------------------------------------------------------------------
// Compacted dbuf GEMM body (R12/R14-proven): 128x128, BK=32, 4 waves,
// 32 KB LDS (hoisted by caller), counted vmcnt(4). Per-lane mapping from the
// wave-uniform gload_lds rule: issue (wid,j) -> LDS base (wid*2+j)*512;
// lane l covers row R=(wid*2+j)*16+(l>>2), 16B slot l&3.
// ---------------------------------------------------------------------------
template<int MODE>
__device__ __forceinline__ void gemm128_body(
        int bid, unsigned short* As, unsigned short* Bs,
        const unsigned short* __restrict__ A,
        const unsigned short* __restrict__ BT,
        const int* __restrict__ meta,
        const int* __restrict__ liveBt,
        const int* __restrict__ grpSrc,
        const int* __restrict__ grpOut,
        unsigned short* __restrict__ o_q,
        unsigned short* __restrict__ o_k,
        unsigned short* __restrict__ o_v,
        float* __restrict__ o_f) {
    constexpr int K     = (MODE == 2) ? 512 : 1024;
    constexpr int NSTEP = K / 32;                              // even
    constexpr int NTSH  = (MODE == 0) ? 2 : 3;                 // log2(N-tiles)

    int lim = (MODE == 1) ? meta[1] : meta[2];
    int L = lim << NTSH;
    if (bid >= L) return;
    int wg = xcd_swz(bid, L);
    int mt = wg >> NTSH;
    int nt = wg & ((1 << NTSH) - 1);
    int n0 = nt * 128;
    int t = threadIdx.x;
    int lane = t & 63, wid = t >> 6;
    int lr = lane & 15, lg = lane >> 4;
    int wm = wid >> 1, wn = wid & 1;

    const unsigned short* aptr[2];
    const unsigned short* bptr[2];
    int grp = wid >> 1;                                    // R>>6 for both j
    #pragma unroll
    for (int j = 0; j < 2; j++) {
        int R   = (wid * 2 + j) * 16 + (lane >> 2);        // row in 128-tile
        int rin = R & 63;                                  // row in 64-group
        size_t srow;
        if (MODE == 0) {
            int bt = liveBt[2 * mt + grp];
            srow = (size_t)bt * NKEY_ + 256 + rin;
        } else if (MODE == 1) {
            srow = (size_t)grpSrc[2 * mt + grp] + rin;
        } else {
            int bt = liveBt[2 * mt + grp];
            srow = (size_t)bt * 64 + rin;
        }
        aptr[j] = A  + srow * K + (lane & 3) * 8;
        bptr[j] = BT + (size_t)(n0 + R) * K + (lane & 3) * 8;
    }

    f32x4 acc[4][4];
    #pragma unroll
    for (int i = 0; i < 4; i++)
        #pragma unroll
        for (int j = 0; j < 4; j++) acc[i][j] = (f32x4){0.f, 0.f, 0.f, 0.f};

    auto stage = [&](int buf) {
        #pragma unroll
        for (int j = 0; j < 2; j++) {
            async16(As + buf * 4096 + (wid * 2 + j) * 512, aptr[j]);
            async16(Bs + buf * 4096 + (wid * 2 + j) * 512, bptr[j]);
            aptr[j] += 32; bptr[j] += 32;
        }
    };
    auto compute = [&](int buf) {
        short8 af[4], bf[4];
        #pragma unroll
        for (int mi = 0; mi < 4; mi++)
            af[mi] = *reinterpret_cast<const short8*>(
                &As[buf * 4096 + (wm * 64 + mi * 16 + lr) * 32 + lg * 8]);
        #pragma unroll
        for (int ni = 0; ni < 4; ni++)
            bf[ni] = *reinterpret_cast<const short8*>(
                &Bs[buf * 4096 + (wn * 64 + ni * 16 + lr) * 32 + lg * 8]);
        #pragma unroll
        for (int mi = 0; mi < 4; mi++)
            #pragma unroll
            for (int ni = 0; ni < 4; ni++)
                acc[mi][ni] = __builtin_amdgcn_mfma_f32_16x16x32_bf16(
                    af[mi], bf[ni], acc[mi][ni], 0, 0, 0);
    };

    #define FULL_STEP(CUR)                                              \
        stage((CUR) ^ 1);                                               \
        asm volatile("s_waitcnt vmcnt(4)" ::: "memory");                \
        __builtin_amdgcn_s_barrier();                                   \
        compute(CUR);                                                   \
        asm volatile("s_waitcnt lgkmcnt(0)" ::: "memory");              \
        __builtin_amdgcn_s_barrier();

    stage(0);
    #pragma unroll 1
    for (int ks2 = 0; ks2 < NSTEP / 2 - 1; ks2++) {
        FULL_STEP(0)
        FULL_STEP(1)
    }
    FULL_STEP(0)
    asm volatile("s_waitcnt vmcnt(0)" ::: "memory");
    __builtin_amdgcn_s_barrier();
    compute(1);
    #undef FULL_STEP

    #pragma unroll
    for (int mi = 0; mi < 4; mi++)
        #pragma unroll
        for (int ni = 0; ni < 4; ni++) {
            int rr = mi * 16 + lg * 4;                     // row in 64-group
            int c  = n0 + wn * 64 + ni * 16 + lr;
            if (MODE == 0) {
                int bt = liveBt[2 * mt + wm];
                #pragma unroll
                for (int r = 0; r < 4; r++)
                    o_q[((size_t)bt * 64 + rr + r) * 512 + c] =
                        f2bf(acc[mi][ni][r] * 0.125f);
            } else if (MODE == 1) {
                int enc = grpOut[2 * mt + wm];
                int bt = enc >> 16, krow = (enc & 0xffff) + rr;
                if (c < 512) {
                    #pragma unroll
                    for (int r = 0; r < 4; r++)
                        o_k[((size_t)bt * NKEY_ + krow + r) * 512 + c] =
                            f2bf(acc[mi][ni][r]);
                } else {
                    ushort4 pv;
                    pv.x = f2bf(acc[mi][ni][0]); pv.y = f2bf(acc[mi][ni][1]);
                    pv.z = f2bf(acc[mi][ni][2]); pv.w = f2bf(acc[mi][ni][3]);
                    *reinterpret_cast<ushort4*>(
                        o_v + ((size_t)bt * 512 + (c - 512)) * NKEY_ + krow) = pv;
                }
            } else {
                int bt = liveBt[2 * mt + wm];
                #pragma unroll
                for (int r = 0; r < 4; r++)
                    o_f[((size_t)bt * 64 + rr + r) * 1024 + c] = acc[mi][ni][r];
            }
        }
}

// fused kv-GEMM (blocks 0..2559) + q-GEMM (blocks 2560..2815)
__global__ __launch_bounds__(256, 4) void gemm_kvq_kernel(
        const unsigned short* __restrict__ kvin,
        const unsigned short* __restrict__ WkvT,
        const unsigned short* __restrict__ WqT,
        const int* __restrict__ meta,
        const int* __restrict__ liveBt,
        const int* __restrict__ grpSrc,
        const int* __restrict__ grpOut,
        unsigned short* __restrict__ o_q,
        unsigned short* __restrict__ o_k,
        unsigned short* __restrict__ o_v) {
    __shared__ __align__(16) unsigned short As[2 * 4096];
    __shared__ __align__(16) unsigned short Bs[2 * 4096];
    int bid = blockIdx.x;
    if (bid < 2560)
        gemm128_body<1>(bid, As, Bs, kvin, WkvT, meta, liveBt, grpSrc, grpOut,
                        o_q, o_k, o_v, (float*)0);
    else
        gemm128_body<0>(bid - 2560, As, Bs, kvin, WqT, meta, liveBt, grpSrc,
                        grpOut, o_q, o_k, o_v, (float*)0);
}

__global__ __launch_bounds__(256, 4) void gemm_out_kernel(
        const unsigned short* __restrict__ ab,
        const unsigned short* __restrict__ WoT,
        const int* __restrict__ meta,
        const int* __restrict__ liveBt,
        const int* __restrict__ grpSrc,
        const int* __restrict__ grpOut,
        float* __restrict__ o_f) {
    __shared__ __align__(16) unsigned short As[2 * 4096];
    __shared__ __align__(16) unsigned short Bs[2 * 4096];
    gemm128_body<2>(blockIdx.x, As, Bs, ab, WoT, meta, liveBt, grpSrc, grpOut,
                    (unsigned short*)0, (unsigned short*)0, (unsigned short*)0,
                    o_f);
}

// ---------------------------------------------------------------------------
// fused attention per live (bt,h) + zero-fill tail (blocks 1024..1151)
// ---------------------------------------------------------------------------
__global__ __launch_bounds__(256) void attn_kernel(
        const unsigned short* __restrict__ q,
        const unsigned short* __restrict__ kbuf,
        const unsigned short* __restrict__ vbuf,   // vT [bt][512][320]
        const int* __restrict__ meta,
        const int* __restrict__ liveBt,
        const int* __restrict__ maskN,
        unsigned short* __restrict__ ao,
        float* __restrict__ out_f) {
    int bid = blockIdx.x;
    if (bid >= 1024) {                             // zero-fill tail
        int bt = bid - 1024;
        if (maskN[bt]) return;
        float4* p = reinterpret_cast<float4*>(out_f + (size_t)bt * 65536);
        float4 z = make_float4(0.f, 0.f, 0.f, 0.f);
        #pragma unroll
        for (int k = 0; k < 64; k++) p[k * 256 + threadIdx.x] = z;
        return;
    }
    int L = meta[0] << 3;
    if (bid >= L) return;
    int wg = xcd_swz(bid, L);
    int i = wg >> 3, h = wg & 7;
    int bt = liveBt[i];
    int t = threadIdx.x, w = t >> 6, lane = t & 63;
    int lr = lane & 15, lg = lane >> 4;
    __shared__ __align__(16) unsigned short attn_s[4][16][328];

    const unsigned short* qrow = q + ((size_t)bt * 64 + w * 16 + lr) * 512 + h * 64;
    short8 qa0 = *reinterpret_cast<const short8*>(qrow + lg * 8);
    short8 qa1 = *reinterpret_cast<const short8*>(qrow + 32 + lg * 8);

    f32x4 acc[20];
    #pragma unroll
    for (int i2 = 0; i2 < 20; i2++) acc[i2] = (f32x4){0.f, 0.f, 0.f, 0.f};

    const unsigned short* kb = kbuf + (size_t)bt * NKEY_ * 512 + h * 64;
    #pragma unroll
    for (int nt2 = 0; nt2 < 20; nt2++) {
        const unsigned short* krow = kb + (size_t)(nt2 * 16 + lr) * 512;
        short8 b0 = *reinterpret_cast<const short8*>(krow + lg * 8);
        short8 b1 = *reinterpret_cast<const short8*>(krow + 32 + lg * 8);
        acc[nt2] = __builtin_amdgcn_mfma_f32_16x16x32_bf16(qa0, b0, acc[nt2], 0, 0, 0);
        acc[nt2] = __builtin_amdgcn_mfma_f32_16x16x32_bf16(qa1, b1, acc[nt2], 0, 0, 0);
    }

    float mx[4], sm[4];
    #pragma unroll
    for (int r = 0; r < 4; r++) mx[r] = -1e30f;
    #pragma unroll
    for (int nt2 = 0; nt2 < 20; nt2++)
        #pragma unroll
        for (int r = 0; r < 4; r++) mx[r] = fmaxf(mx[r], acc[nt2][r]);
    #pragma unroll
    for (int r = 0; r < 4; r++) {
        #pragma unroll
        for (int off = 1; off < 16; off <<= 1)
            mx[r] = fmaxf(mx[r], __shfl_xor(mx[r], off));
        sm[r] = 0.f;
    }
    #pragma unroll
    for (int nt2 = 0; nt2 < 20; nt2++)
        #pragma unroll
        for (int r = 0; r < 4; r++) {
            float p = __expf(acc[nt2][r] - mx[r]);
            acc[nt2][r] = p;
            sm[r] += p;
        }
    #pragma unroll
    for (int r = 0; r < 4; r++) {
        #pragma unroll
        for (int off = 1; off < 16; off <<= 1)
            sm[r] += __shfl_xor(sm[r], off);
        sm[r] = 1.0f / sm[r];
    }
    #pragma unroll
    for (int nt2 = 0; nt2 < 20; nt2++)
        #pragma unroll
        for (int r = 0; r < 4; r++)
            attn_s[w][lg * 4 + r][nt2 * 16 + lr] = f2bf(acc[nt2][r] * sm[r]);
    __syncthreads();

    f32x4 o[4];
    #pragma unroll
    for (int i2 = 0; i2 < 4; i2++) o[i2] = (f32x4){0.f, 0.f, 0.f, 0.f};
    const unsigned short* vb = vbuf + (size_t)bt * 512 * NKEY_ + (size_t)h * 64 * NKEY_;
    #pragma unroll
    for (int kc = 0; kc < 10; kc++) {
        short8 pa = *reinterpret_cast<const short8*>(&attn_s[w][lr][kc * 32 + lg * 8]);
        #pragma unroll
        for (int ni = 0; ni < 4; ni++) {
            short8 vf = *reinterpret_cast<const short8*>(
                vb + (size_t)(ni * 16 + lr) * NKEY_ + kc * 32 + lg * 8);
            o[ni] = __builtin_amdgcn_mfma_f32_16x16x32_bf16(pa, vf, o[ni], 0, 0, 0);
        }
    }
    #pragma unroll
    for (int ni = 0; ni < 4; ni++)
        #pragma unroll
        for (int r = 0; r < 4; r++)
            ao[((size_t)bt * 64 + w * 16 + lg * 4 + r) * 512 + h * 64 + ni * 16 + lr] =
                f2bf(o[ni][r]);
}

// ---------------------------------------------------------------------------
extern "C" void kernel_launch(void* const* d_in, const int* in_sizes, int n_in,
                              void* d_out, int out_size, void* d_ws, size_t ws_size,
                              hipStream_t stream) {
    const float* x            = (const float*)d_in[0];
    const float* lat          = (const float*)d_in[1];
    const unsigned char* mraw = (const unsigned char*)d_in[2];
    const float* gm           = (const float*)d_in[3];
    const float* bm           = (const float*)d_in[4];
    const float* gl           = (const float*)d_in[5];
    const float* bl           = (const float*)d_in[6];
    const float* Wq           = (const float*)d_in[7];
    const float* Wkv          = (const float*)d_in[8];
    const float* Wo           = (const float*)d_in[9];
    float* out = (float*)d_out;

    char* ws = (char*)d_ws;
    int* maskN  = (int*)(ws + 0);          // 512 B
    int* meta   = (int*)(ws + 512);        // 64 B
    int* liveBt = (int*)(ws + 1024);       // 640 B
    int* grpSrc = (int*)(ws + 2048);       // ~2.6 KB
    int* grpOut = (int*)(ws + 5120);       // ~2.6 KB
    size_t off = 8192;
    unsigned short* WqT  = (unsigned short*)(ws + off); off += 1048576;   // 512*1024*2
    unsigned short* WkvT = (unsigned short*)(ws + off); off += 2097152;   // 1024*1024*2
    unsigned short* WoT  = (unsigned short*)(ws + off); off += 1048576;   // 1024*512*2
    unsigned short* kvin = (unsigned short*)(ws + off); off += 83886080;  // 128*320*1024*2
    unsigned short* qb   = (unsigned short*)(ws + off); off += 8388608;   // 128*64*512*2
    unsigned short* kb   = (unsigned short*)(ws + off); off += 41943040;  // 128*320*512*2
    unsigned short* vb   = (unsigned short*)(ws + off); off += 41943040;  // 128*512*320*2
    unsigned short* ab   = (unsigned short*)(ws + off); off += 8388608;   // 128*64*512*2

    hipLaunchKernelGGL(prep_ln_kernel, dim3(41473), dim3(256), 0, stream,
                       Wq, Wkv, Wo, mraw, x, lat, gm, bm, gl, bl,
                       WqT, WkvT, WoT, kvin, maskN, meta, liveBt, grpSrc, grpOut);
    hipLaunchKernelGGL(gemm_kvq_kernel, dim3(2816), dim3(256), 0, stream,
                       kvin, WkvT, WqT, meta, liveBt, grpSrc, grpOut,
                       qb, kb, vb);
    hipLaunchKernelGGL(attn_kernel,     dim3(1152), dim3(256), 0, stream,
                       qb, kb, vb, meta, liveBt, maskN, ab, out);
    hipLaunchKernelGGL(gemm_out_kernel, dim3(512),  dim3(256), 0, stream,
                       ab, WoT, meta, liveBt, grpSrc, grpOut, out);
}